// Round 6
// baseline (159.912 us; speedup 1.0000x reference)
//
#include <hip/hip_runtime.h>
#include <math.h>

// Problem constants
constexpr int NB = 2;        // batch
constexpr int LQ = 2048;     // sequence length
constexpr int DD = 512;      // model dim
constexpr int PPL = 16;      // planes per set
constexpr int TPP = 64;      // total planes (S*P)
constexpr int FF = 128;      // feature dim = 2*TPP (cos,sin interleaved)
constexpr int NC = 32;       // chunks
constexpr int TC = 64;       // chunk length
constexpr float PI_F = 3.14159265358979323846f;

typedef __attribute__((ext_vector_type(4))) float f32x4;
typedef __attribute__((ext_vector_type(8))) short bf16x8;

static __device__ __forceinline__ unsigned short f2bf(float x) {
    union { float f; unsigned u; } v; v.f = x;
    unsigned r = v.u + 0x7fff + ((v.u >> 16) & 1);
    return (unsigned short)(r >> 16);
}
static __device__ __forceinline__ float bf2f(unsigned short u) {
    union { unsigned u; float f; } v; v.u = ((unsigned)u) << 16;
    return v.f;
}

// ---------------- prep: cast x->bf16 + all weight transposes, one launch ----------------
// flat grid: [0,1024) cast; [1024,2048) 512x512 transposes (4 mats); [2048,2112) 512x64 (2 mats)
__global__ __launch_bounds__(256) void prep_kernel(
    const float* __restrict__ x,
    const float* __restrict__ kw1, const float* __restrict__ qw1,
    const float* __restrict__ vw, const float* __restrict__ ow,
    const float* __restrict__ kw2, const float* __restrict__ qw2,
    unsigned short* __restrict__ xb,
    unsigned short* __restrict__ kw1t, unsigned short* __restrict__ qw1t,
    unsigned short* __restrict__ vwt, unsigned short* __restrict__ owt,
    unsigned short* __restrict__ kw2t, unsigned short* __restrict__ qw2t)
{
    __shared__ float t[32][33];
    const int id = blockIdx.x;
    const int tid = threadIdx.x;
    if (id < 1024) {                       // cast 2M elements
        const int i = id * 2048 + tid * 8;
        float4 a = *(const float4*)(x + i);
        float4 b = *(const float4*)(x + i + 4);
        ushort4 u0 = {f2bf(a.x), f2bf(a.y), f2bf(a.z), f2bf(a.w)};
        ushort4 u1 = {f2bf(b.x), f2bf(b.y), f2bf(b.z), f2bf(b.w)};
        *(ushort4*)(xb + i) = u0;
        *(ushort4*)(xb + i + 4) = u1;
        return;
    }
    const float* W;
    unsigned short* O;
    int K, N, n0, k0;
    if (id < 2048) {                       // 512x512 transposes
        const int rid = id - 1024;
        const int mat = rid >> 8, rem = rid & 255;
        W = (mat == 0) ? kw1 : (mat == 1) ? qw1 : (mat == 2) ? vw : ow;
        O = (mat == 0) ? kw1t : (mat == 1) ? qw1t : (mat == 2) ? vwt : owt;
        K = DD; N = DD;
        n0 = (rem & 15) * 32; k0 = (rem >> 4) * 32;
    } else {                               // 512x64 transposes
        const int rid = id - 2048;
        const int mat = rid >> 5, rem = rid & 31;
        W = mat ? qw2 : kw2;
        O = mat ? qw2t : kw2t;
        K = DD; N = TPP;
        n0 = (rem & 1) * 32; k0 = (rem >> 1) * 32;
    }
    const int tx = tid & 31, ty = tid >> 5;  // 32x8
#pragma unroll
    for (int i = 0; i < 4; ++i)
        t[ty + 8 * i][tx] = W[(size_t)(k0 + ty + 8 * i) * N + n0 + tx];
    __syncthreads();
#pragma unroll
    for (int i = 0; i < 4; ++i)
        O[(size_t)(n0 + ty + 8 * i) * K + k0 + tx] = f2bf(t[tx][ty + 8 * i]);
}

// ---------------- fused x-GEMMs: z=0 -> gelu->hkb, z=1 -> gelu->hqb, z=2 -> Vt ----------------
// BM=128, BN=64, BK=64, 256 thr (4 waves, wave tile 64x32). A,Bt k-contiguous bf16.
__global__ __launch_bounds__(256) void mgemm_fused(
    const unsigned short* __restrict__ A,
    const unsigned short* __restrict__ kw1t, const unsigned short* __restrict__ qw1t,
    const unsigned short* __restrict__ vwt,
    const float* __restrict__ kb1, const float* __restrict__ qb1, const float* __restrict__ vb,
    unsigned short* __restrict__ hkb, unsigned short* __restrict__ hqb,
    unsigned short* __restrict__ Vt)
{
    const int z = blockIdx.z;
    const unsigned short* Bt = (z == 0) ? kw1t : (z == 1) ? qw1t : vwt;
    const float* bias = (z == 0) ? kb1 : (z == 1) ? qb1 : vb;
    unsigned short* obf = (z == 0) ? hkb : (z == 1) ? hqb : Vt;
    const int K = DD, N = DD;

    __shared__ unsigned short As[128 * 72];
    __shared__ unsigned short Bs[64 * 72];
    const int tid = threadIdx.x;
    const int w = tid >> 6, lane = tid & 63, grp = lane >> 4, lid = lane & 15;
    const int wr = w >> 1, wc = w & 1;
    const int row0 = blockIdx.y * 128, col0 = blockIdx.x * 64;
    f32x4 acc[4][2];
#pragma unroll
    for (int m = 0; m < 4; ++m)
#pragma unroll
        for (int n = 0; n < 2; ++n) acc[m][n] = (f32x4)0.f;

    for (int k0 = 0; k0 < K; k0 += 64) {
        bf16x8 va[4], vbv[2];
#pragma unroll
        for (int i = 0; i < 4; ++i) {
            const int c = tid + i * 256;
            va[i] = *(const bf16x8*)(A + (size_t)(row0 + (c >> 3)) * K + k0 + (c & 7) * 8);
        }
#pragma unroll
        for (int i = 0; i < 2; ++i) {
            const int c = tid + i * 256;
            vbv[i] = *(const bf16x8*)(Bt + (size_t)(col0 + (c >> 3)) * K + k0 + (c & 7) * 8);
        }
        __syncthreads();
#pragma unroll
        for (int i = 0; i < 4; ++i) {
            const int c = tid + i * 256;
            *(bf16x8*)(As + (c >> 3) * 72 + (c & 7) * 8) = va[i];
        }
#pragma unroll
        for (int i = 0; i < 2; ++i) {
            const int c = tid + i * 256;
            *(bf16x8*)(Bs + (c >> 3) * 72 + (c & 7) * 8) = vbv[i];
        }
        __syncthreads();
#pragma unroll
        for (int kk = 0; kk < 2; ++kk) {
            bf16x8 af[4], bfr[2];
#pragma unroll
            for (int m = 0; m < 4; ++m)
                af[m] = *(const bf16x8*)(As + (wr * 64 + m * 16 + lid) * 72 + kk * 32 + grp * 8);
#pragma unroll
            for (int n = 0; n < 2; ++n)
                bfr[n] = *(const bf16x8*)(Bs + (wc * 32 + n * 16 + lid) * 72 + kk * 32 + grp * 8);
#pragma unroll
            for (int m = 0; m < 4; ++m)
#pragma unroll
                for (int n = 0; n < 2; ++n)
                    acc[m][n] = __builtin_amdgcn_mfma_f32_16x16x32_bf16(af[m], bfr[n], acc[m][n], 0, 0, 0);
        }
    }
#pragma unroll
    for (int m = 0; m < 4; ++m) {
#pragma unroll
        for (int n = 0; n < 2; ++n) {
            const int col = col0 + wc * 32 + n * 16 + lid;
            const float bc = bias[col];
            if (z == 2) {
                const int rowb = row0 + wr * 64 + m * 16 + grp * 4;
                const int b = rowb >> 11, l = rowb & (LQ - 1);
                const int c = l >> 6, t0 = l & 63;
                ushort4 u;
                u.x = f2bf(acc[m][n][0] + bc);
                u.y = f2bf(acc[m][n][1] + bc);
                u.z = f2bf(acc[m][n][2] + bc);
                u.w = f2bf(acc[m][n][3] + bc);
                *(ushort4*)(Vt + ((size_t)((b * NC + c) * DD) + col) * TC + t0) = u;
            } else {
#pragma unroll
                for (int r = 0; r < 4; ++r) {
                    const int row = row0 + wr * 64 + m * 16 + grp * 4 + r;
                    float v = acc[m][n][r] + bc;
                    v = 0.5f * v * (1.0f + erff(v * 0.70710678118654752f));
                    obf[(size_t)row * N + col] = f2bf(v);
                }
            }
        }
    }
}

// ---------------- fused phase GEMM: y=0 -> K features, y=1 -> Q features ----------------
// BM=64, N=64, K=512. 4 waves, wave tile 16 rows x 64 cols.
__global__ __launch_bounds__(256) void phase_fused(
    const unsigned short* __restrict__ hkb, const unsigned short* __restrict__ hqb,
    const unsigned short* __restrict__ kw2t, const unsigned short* __restrict__ qw2t,
    const float* __restrict__ kb2, const float* __restrict__ qb2,
    const float* __restrict__ sw,
    unsigned short* __restrict__ CKb, unsigned short* __restrict__ CQb,
    unsigned short* __restrict__ CKt)
{
    const int isq = blockIdx.y;
    const unsigned short* A = isq ? hqb : hkb;
    const unsigned short* Bt = isq ? qw2t : kw2t;
    const float* b2 = isq ? qb2 : kb2;
    unsigned short* FROW = isq ? CQb : CKb;
    const int K = DD;

    __shared__ unsigned short As[64 * 72];
    __shared__ unsigned short Bs[64 * 72];
    const int tid = threadIdx.x;
    const int w = tid >> 6, lane = tid & 63, grp = lane >> 4, lid = lane & 15;
    const int row0 = blockIdx.x * 64;
    f32x4 acc[4];
#pragma unroll
    for (int n = 0; n < 4; ++n) acc[n] = (f32x4)0.f;

    for (int k0 = 0; k0 < K; k0 += 64) {
        bf16x8 va[2], vbv[2];
#pragma unroll
        for (int i = 0; i < 2; ++i) {
            const int c = tid + i * 256;
            va[i] = *(const bf16x8*)(A + (size_t)(row0 + (c >> 3)) * K + k0 + (c & 7) * 8);
            vbv[i] = *(const bf16x8*)(Bt + (size_t)(c >> 3) * K + k0 + (c & 7) * 8);
        }
        __syncthreads();
#pragma unroll
        for (int i = 0; i < 2; ++i) {
            const int c = tid + i * 256;
            *(bf16x8*)(As + (c >> 3) * 72 + (c & 7) * 8) = va[i];
            *(bf16x8*)(Bs + (c >> 3) * 72 + (c & 7) * 8) = vbv[i];
        }
        __syncthreads();
#pragma unroll
        for (int kk = 0; kk < 2; ++kk) {
            bf16x8 af, bfr[4];
            af = *(const bf16x8*)(As + (w * 16 + lid) * 72 + kk * 32 + grp * 8);
#pragma unroll
            for (int n = 0; n < 4; ++n)
                bfr[n] = *(const bf16x8*)(Bs + (n * 16 + lid) * 72 + kk * 32 + grp * 8);
#pragma unroll
            for (int n = 0; n < 4; ++n)
                acc[n] = __builtin_amdgcn_mfma_f32_16x16x32_bf16(af, bfr[n], acc[n], 0, 0, 0);
        }
    }
    float wsm[4] = {1.f, 1.f, 1.f, 1.f};
    if (isq) {
        float s0 = sw[0], s1 = sw[1], s2 = sw[2], s3 = sw[3];
        float mx = fmaxf(fmaxf(s0, s1), fmaxf(s2, s3));
        float e0 = expf(s0 - mx), e1 = expf(s1 - mx), e2 = expf(s2 - mx), e3 = expf(s3 - mx);
        float inv = 1.0f / (e0 + e1 + e2 + e3);
        wsm[0] = e0 * inv; wsm[1] = e1 * inv; wsm[2] = e2 * inv; wsm[3] = e3 * inv;
    }
#pragma unroll
    for (int n = 0; n < 4; ++n) {
        const int p = n * 16 + lid;
        const float bc = b2[p];
        const float wg = isq ? wsm[p >> 4] : 1.0f;
#pragma unroll
        for (int r = 0; r < 4; ++r) {
            const int row = row0 + w * 16 + grp * 4 + r;
            float u = acc[n][r] + bc;
            float ph = tanhf(u) * PI_F;
            float sp, cp;
            sincosf(ph, &sp, &cp);
            const unsigned short cb = f2bf(cp * wg), sb = f2bf(sp * wg);
            FROW[(size_t)row * FF + 2 * p + 0] = cb;
            FROW[(size_t)row * FF + 2 * p + 1] = sb;
            if (!isq) {
                const int b = row >> 11, l = row & (LQ - 1);
                const int c = l >> 6, t = l & 63;
                const size_t base = ((size_t)(b * NC + c) * FF) * TC;
                CKt[base + (size_t)(2 * p + 0) * TC + t] = cb;
                CKt[base + (size_t)(2 * p + 1) * TC + t] = sb;
            }
        }
    }
}

// ---------------- pass A: per-chunk state (bf16) Stp[b][c][d][f] = sum_t Vt[d][t]*CKt[f][t] ----------------
__global__ __launch_bounds__(256) void passA_mfma(
    const unsigned short* __restrict__ Vt, const unsigned short* __restrict__ CKt,
    unsigned short* __restrict__ Stp)
{
    const int tid = threadIdx.x;
    const int w = tid >> 6, lane = tid & 63, grp = lane >> 4, lid = lane & 15;
    const int dq = blockIdx.x, c = blockIdx.y, b = blockIdx.z;
    const int d0 = dq * 128 + w * 32;
    const size_t cb = (size_t)(b * NC + c);
    f32x4 acc[2][8];
#pragma unroll
    for (int md = 0; md < 2; ++md)
#pragma unroll
        for (int nf = 0; nf < 8; ++nf) acc[md][nf] = (f32x4)0.f;
#pragma unroll
    for (int kt = 0; kt < 2; ++kt) {
        bf16x8 av[2], bk[8];
#pragma unroll
        for (int md = 0; md < 2; ++md)
            av[md] = *(const bf16x8*)(Vt + (cb * DD + d0 + md * 16 + lid) * TC + kt * 32 + grp * 8);
#pragma unroll
        for (int nf = 0; nf < 8; ++nf)
            bk[nf] = *(const bf16x8*)(CKt + (cb * FF + nf * 16 + lid) * TC + kt * 32 + grp * 8);
#pragma unroll
        for (int md = 0; md < 2; ++md)
#pragma unroll
            for (int nf = 0; nf < 8; ++nf)
                acc[md][nf] = __builtin_amdgcn_mfma_f32_16x16x32_bf16(av[md], bk[nf], acc[md][nf], 0, 0, 0);
    }
#pragma unroll
    for (int md = 0; md < 2; ++md)
#pragma unroll
        for (int nf = 0; nf < 8; ++nf)
#pragma unroll
            for (int r = 0; r < 4; ++r) {
                const int d = d0 + md * 16 + grp * 4 + r;
                const int f = nf * 16 + lid;
                Stp[(cb * DD + d) * FF + f] = f2bf(acc[md][nf][r]);
            }
}

// ---------------- pass B: exclusive prefix over chunks (bf16 in, f32 run, bf16 out) ----------------
__global__ __launch_bounds__(256) void prefix_mfma(
    const unsigned short* __restrict__ Stp, unsigned short* __restrict__ Stb)
{
    const int gid = blockIdx.x * 256 + threadIdx.x;  // b*(DD*FF) + d*FF + f
    const int b = gid >> 16;                          // DD*FF = 65536
    const int df = gid & 65535;
    float run = 0.f;
#pragma unroll
    for (int c = 0; c < NC; ++c) {
        const size_t idx = ((size_t)(b * NC + c) << 16) + df;
        Stb[idx] = f2bf(run);
        run += bf2f(Stp[idx]);
    }
}

// ---------------- pass C: r = tril(CQ CK^T) V + CQ S_prefix ----------------
__global__ __launch_bounds__(128) void passC_mfma(
    const unsigned short* __restrict__ CQb, const unsigned short* __restrict__ CKb,
    const unsigned short* __restrict__ Vt, const unsigned short* __restrict__ Stb,
    float* __restrict__ R)
{
    __shared__ unsigned short P[64][72];
    const int tid = threadIdx.x;
    const int w = tid >> 6, lane = tid & 63, grp = lane >> 4, lid = lane & 15;
    const int dh = blockIdx.x, c = blockIdx.y, b = blockIdx.z;
    const size_t rowbase = (size_t)b * LQ + c * 64;
    const size_t cb = (size_t)(b * NC + c);
    f32x4 qk[2][4];
#pragma unroll
    for (int mi = 0; mi < 2; ++mi)
#pragma unroll
        for (int nt = 0; nt < 4; ++nt) qk[mi][nt] = (f32x4)0.f;
#pragma unroll
    for (int kf = 0; kf < 4; ++kf) {
        bf16x8 aq[2], bk[4];
#pragma unroll
        for (int mi = 0; mi < 2; ++mi)
            aq[mi] = *(const bf16x8*)(CQb + (rowbase + (2 * w + mi) * 16 + lid) * FF + kf * 32 + grp * 8);
#pragma unroll
        for (int nt = 0; nt < 4; ++nt)
            bk[nt] = *(const bf16x8*)(CKb + (rowbase + nt * 16 + lid) * FF + kf * 32 + grp * 8);
#pragma unroll
        for (int mi = 0; mi < 2; ++mi)
#pragma unroll
            for (int nt = 0; nt < 4; ++nt)
                qk[mi][nt] = __builtin_amdgcn_mfma_f32_16x16x32_bf16(aq[mi], bk[nt], qk[mi][nt], 0, 0, 0);
    }
#pragma unroll
    for (int mi = 0; mi < 2; ++mi)
#pragma unroll
        for (int nt = 0; nt < 4; ++nt)
#pragma unroll
            for (int r = 0; r < 4; ++r) {
                const int row = (2 * w + mi) * 16 + grp * 4 + r;
                const int col = nt * 16 + lid;
                P[row][col] = f2bf(col <= row ? qk[mi][nt][r] : 0.f);
            }
    __syncthreads();
    const int d0 = dh * 128 + w * 64;
    f32x4 racc[4][4];
#pragma unroll
    for (int ml = 0; ml < 4; ++ml)
#pragma unroll
        for (int nd = 0; nd < 4; ++nd) racc[ml][nd] = (f32x4)0.f;
#pragma unroll
    for (int kt = 0; kt < 2; ++kt) {
        bf16x8 ap[4], bv[4];
#pragma unroll
        for (int ml = 0; ml < 4; ++ml)
            ap[ml] = *(const bf16x8*)&P[ml * 16 + lid][kt * 32 + grp * 8];
#pragma unroll
        for (int nd = 0; nd < 4; ++nd)
            bv[nd] = *(const bf16x8*)(Vt + (cb * DD + d0 + nd * 16 + lid) * TC + kt * 32 + grp * 8);
#pragma unroll
        for (int ml = 0; ml < 4; ++ml)
#pragma unroll
            for (int nd = 0; nd < 4; ++nd)
                racc[ml][nd] = __builtin_amdgcn_mfma_f32_16x16x32_bf16(ap[ml], bv[nd], racc[ml][nd], 0, 0, 0);
    }
#pragma unroll
    for (int kf = 0; kf < 4; ++kf) {
        bf16x8 aq[4], bs[4];
#pragma unroll
        for (int ml = 0; ml < 4; ++ml)
            aq[ml] = *(const bf16x8*)(CQb + (rowbase + ml * 16 + lid) * FF + kf * 32 + grp * 8);
#pragma unroll
        for (int nd = 0; nd < 4; ++nd)
            bs[nd] = *(const bf16x8*)(Stb + (cb * DD + d0 + nd * 16 + lid) * FF + kf * 32 + grp * 8);
#pragma unroll
        for (int ml = 0; ml < 4; ++ml)
#pragma unroll
            for (int nd = 0; nd < 4; ++nd)
                racc[ml][nd] = __builtin_amdgcn_mfma_f32_16x16x32_bf16(aq[ml], bs[nd], racc[ml][nd], 0, 0, 0);
    }
#pragma unroll
    for (int ml = 0; ml < 4; ++ml)
#pragma unroll
        for (int nd = 0; nd < 4; ++nd)
#pragma unroll
            for (int r = 0; r < 4; ++r) {
                const int l = ml * 16 + grp * 4 + r;
                const int d = d0 + nd * 16 + lid;
                R[(rowbase + l) * DD + d] = racc[ml][nd][r];
            }
}

// ---------------- fused LN + output GEMM ----------------
// BM=64, BN=64, K=512. LN stats over k computed in prologue, normalization fused into A staging.
__global__ __launch_bounds__(256) void ln_out_gemm(
    const float* __restrict__ Rb, const float* __restrict__ g,
    const float* __restrict__ be, const unsigned short* __restrict__ Bt,
    const float* __restrict__ bias, const float* __restrict__ resid,
    float* __restrict__ out)
{
    const int K = DD, N = DD;
    __shared__ unsigned short As[64 * 72];
    __shared__ unsigned short Bs[64 * 72];
    __shared__ float smu[64], srs[64], sps[64], sg[512], sbe[512];
    const int tid = threadIdx.x;
    const int w = tid >> 6, lane = tid & 63, grp = lane >> 4, lid = lane & 15;
    const int wr = w >> 1, wc = w & 1;
    const int row0 = blockIdx.y * 64, col0 = blockIdx.x * 64;

    sg[tid] = g[tid]; sg[tid + 256] = g[tid + 256];
    sbe[tid] = be[tid]; sbe[tid + 256] = be[tid + 256];

    // per-row stats: 4 threads per row, 128 k each
    {
        const int rr = tid >> 2, seg = tid & 3;
        const float* rp = Rb + (size_t)(row0 + rr) * DD + seg * 128;
        float s = 0.f, q = 0.f;
#pragma unroll
        for (int j = 0; j < 32; ++j) {
            float4 v = *(const float4*)(rp + j * 4);
            s += v.x + v.y + v.z + v.w;
            q += v.x * v.x + v.y * v.y + v.z * v.z + v.w * v.w;
        }
        s += __shfl_xor(s, 1, 64); q += __shfl_xor(q, 1, 64);
        s += __shfl_xor(s, 2, 64); q += __shfl_xor(q, 2, 64);
        if (seg == 0) {
            const int l = (row0 + rr) & (LQ - 1);
            const float ps = rsqrtf((float)((l + 1) * PPL));
            const float mu = s * (1.0f / DD) * ps;
            const float ey2 = q * (1.0f / DD) * ps * ps;
            smu[rr] = mu;
            srs[rr] = rsqrtf(ey2 - mu * mu + 1e-5f);
            sps[rr] = ps;
        }
    }
    __syncthreads();

    f32x4 acc[2][2];
#pragma unroll
    for (int m = 0; m < 2; ++m)
#pragma unroll
        for (int n = 0; n < 2; ++n) acc[m][n] = (f32x4)0.f;

    for (int k0 = 0; k0 < K; k0 += 64) {
        ushort4 ua[2][2];
        bf16x8 vbv[2];
#pragma unroll
        for (int i = 0; i < 2; ++i) {
            const int c = tid + i * 256;
            const int r = c >> 3, kb = (c & 7) * 8;
            const float mu = smu[r], rs = srs[r], ps = sps[r];
            const float* rp = Rb + (size_t)(row0 + r) * DD + k0 + kb;
            float4 a0 = *(const float4*)rp;
            float4 a1 = *(const float4*)(rp + 4);
            const float* gg = sg + k0 + kb;
            const float* bb = sbe + k0 + kb;
            ua[i][0].x = f2bf((a0.x * ps - mu) * rs * gg[0] + bb[0]);
            ua[i][0].y = f2bf((a0.y * ps - mu) * rs * gg[1] + bb[1]);
            ua[i][0].z = f2bf((a0.z * ps - mu) * rs * gg[2] + bb[2]);
            ua[i][0].w = f2bf((a0.w * ps - mu) * rs * gg[3] + bb[3]);
            ua[i][1].x = f2bf((a1.x * ps - mu) * rs * gg[4] + bb[4]);
            ua[i][1].y = f2bf((a1.y * ps - mu) * rs * gg[5] + bb[5]);
            ua[i][1].z = f2bf((a1.z * ps - mu) * rs * gg[6] + bb[6]);
            ua[i][1].w = f2bf((a1.w * ps - mu) * rs * gg[7] + bb[7]);
            vbv[i] = *(const bf16x8*)(Bt + (size_t)(col0 + r) * K + k0 + kb);
        }
        __syncthreads();
#pragma unroll
        for (int i = 0; i < 2; ++i) {
            const int c = tid + i * 256;
            *(ushort4*)(As + (c >> 3) * 72 + (c & 7) * 8) = ua[i][0];
            *(ushort4*)(As + (c >> 3) * 72 + (c & 7) * 8 + 4) = ua[i][1];
            *(bf16x8*)(Bs + (c >> 3) * 72 + (c & 7) * 8) = vbv[i];
        }
        __syncthreads();
#pragma unroll
        for (int kk = 0; kk < 2; ++kk) {
            bf16x8 af[2], bfr[2];
#pragma unroll
            for (int m = 0; m < 2; ++m)
                af[m] = *(const bf16x8*)(As + (wr * 32 + m * 16 + lid) * 72 + kk * 32 + grp * 8);
#pragma unroll
            for (int n = 0; n < 2; ++n)
                bfr[n] = *(const bf16x8*)(Bs + (wc * 32 + n * 16 + lid) * 72 + kk * 32 + grp * 8);
#pragma unroll
            for (int m = 0; m < 2; ++m)
#pragma unroll
                for (int n = 0; n < 2; ++n)
                    acc[m][n] = __builtin_amdgcn_mfma_f32_16x16x32_bf16(af[m], bfr[n], acc[m][n], 0, 0, 0);
        }
    }
#pragma unroll
    for (int m = 0; m < 2; ++m) {
#pragma unroll
        for (int n = 0; n < 2; ++n) {
            const int col = col0 + wc * 32 + n * 16 + lid;
            const float bc = bias[col];
#pragma unroll
            for (int r = 0; r < 4; ++r) {
                const int row = row0 + wr * 32 + m * 16 + grp * 4 + r;
                out[(size_t)row * N + col] = acc[m][n][r] + bc + resid[(size_t)row * N + col];
            }
        }
    }
}

extern "C" void kernel_launch(void* const* d_in, const int* in_sizes, int n_in,
                              void* d_out, int out_size, void* d_ws, size_t ws_size,
                              hipStream_t stream)
{
    const float* x   = (const float*)d_in[0];
    const float* sw  = (const float*)d_in[1];
    const float* kw1 = (const float*)d_in[2];
    const float* kb1 = (const float*)d_in[3];
    const float* kw2 = (const float*)d_in[4];
    const float* kb2 = (const float*)d_in[5];
    const float* qw1 = (const float*)d_in[6];
    const float* qb1 = (const float*)d_in[7];
    const float* qw2 = (const float*)d_in[8];
    const float* qb2 = (const float*)d_in[9];
    const float* vw  = (const float*)d_in[10];
    const float* vb  = (const float*)d_in[11];
    const float* lng = (const float*)d_in[12];
    const float* lnb = (const float*)d_in[13];
    const float* ow  = (const float*)d_in[14];
    const float* ob  = (const float*)d_in[15];
    float* out = (float*)d_out;

    const size_t MR = (size_t)NB * LQ;  // 4096 rows
    float* ws = (float*)d_ws;
    float* Rb = ws;                                   // 2M f32
    unsigned short* xb   = (unsigned short*)(Rb + MR * DD);
    unsigned short* hkb  = xb + MR * DD;
    unsigned short* hqb  = hkb + MR * DD;
    unsigned short* Vt   = hqb + MR * DD;
    unsigned short* CQb  = Vt + MR * DD;
    unsigned short* CKb  = CQb + MR * FF;
    unsigned short* CKt  = CKb + MR * FF;
    unsigned short* Stp  = CKt + MR * FF;             // 4M shorts
    unsigned short* Stb  = Stp + (size_t)NB * NC * DD * FF;  // 4M shorts
    unsigned short* kw1t = Stb + (size_t)NB * NC * DD * FF;
    unsigned short* qw1t = kw1t + (size_t)DD * DD;
    unsigned short* vwt  = qw1t + (size_t)DD * DD;
    unsigned short* owt  = vwt + (size_t)DD * DD;
    unsigned short* kw2t = owt + (size_t)DD * DD;
    unsigned short* qw2t = kw2t + (size_t)TPP * DD;

    const dim3 blk(256);
    hipLaunchKernelGGL(prep_kernel, dim3(2112), blk, 0, stream,
                       x, kw1, qw1, vw, ow, kw2, qw2,
                       xb, kw1t, qw1t, vwt, owt, kw2t, qw2t);
    hipLaunchKernelGGL(mgemm_fused, dim3(DD / 64, MR / 128, 3), blk, 0, stream,
                       xb, kw1t, qw1t, vwt, kb1, qb1, vb, hkb, hqb, Vt);
    hipLaunchKernelGGL(phase_fused, dim3(MR / 64, 2), blk, 0, stream,
                       hkb, hqb, kw2t, qw2t, kb2, qb2, sw, CKb, CQb, CKt);
    hipLaunchKernelGGL(passA_mfma, dim3(4, NC, NB), blk, 0, stream, Vt, CKt, Stp);
    hipLaunchKernelGGL(prefix_mfma, dim3((NB * DD * FF) / 256), blk, 0, stream, Stp, Stb);
    hipLaunchKernelGGL(passC_mfma, dim3(4, NC, NB), dim3(128), 0, stream, CQb, CKb, Vt, Stb, Rb);
    hipLaunchKernelGGL(ln_out_gemm, dim3(DD / 64, MR / 64), blk, 0, stream,
                       Rb, lng, lnb, owt, ob, x, out);
}

// Round 8
// 154.101 us; speedup vs baseline: 1.0377x; 1.0377x over previous
//
#include <hip/hip_runtime.h>
#include <math.h>

// Problem constants
constexpr int NB = 2;        // batch
constexpr int LQ = 2048;     // sequence length
constexpr int DD = 512;      // model dim
constexpr int PPL = 16;      // planes per set
constexpr int TPP = 64;      // total planes (S*P)
constexpr int FF = 128;      // feature dim = 2*TPP (cos,sin interleaved)
constexpr int NC = 32;       // chunks
constexpr int TC = 64;       // chunk length
constexpr float PI_F = 3.14159265358979323846f;

typedef __attribute__((ext_vector_type(4))) float f32x4;
typedef __attribute__((ext_vector_type(8))) short bf16x8;

static __device__ __forceinline__ unsigned short f2bf(float x) {
    union { float f; unsigned u; } v; v.f = x;
    unsigned r = v.u + 0x7fff + ((v.u >> 16) & 1);
    return (unsigned short)(r >> 16);
}
static __device__ __forceinline__ float bf2f(unsigned short u) {
    union { unsigned u; float f; } v; v.u = ((unsigned)u) << 16;
    return v.f;
}

// ---------------- prep: cast x->bf16 + all weight transposes, one launch ----------------
__global__ __launch_bounds__(256) void prep_kernel(
    const float* __restrict__ x,
    const float* __restrict__ kw1, const float* __restrict__ qw1,
    const float* __restrict__ vw, const float* __restrict__ ow,
    const float* __restrict__ kw2, const float* __restrict__ qw2,
    unsigned short* __restrict__ xb,
    unsigned short* __restrict__ kw1t, unsigned short* __restrict__ qw1t,
    unsigned short* __restrict__ vwt, unsigned short* __restrict__ owt,
    unsigned short* __restrict__ kw2t, unsigned short* __restrict__ qw2t)
{
    __shared__ float t[32][33];
    const int id = blockIdx.x;
    const int tid = threadIdx.x;
    if (id < 1024) {                       // cast 2M elements
        const int i = id * 2048 + tid * 8;
        float4 a = *(const float4*)(x + i);
        float4 b = *(const float4*)(x + i + 4);
        ushort4 u0 = {f2bf(a.x), f2bf(a.y), f2bf(a.z), f2bf(a.w)};
        ushort4 u1 = {f2bf(b.x), f2bf(b.y), f2bf(b.z), f2bf(b.w)};
        *(ushort4*)(xb + i) = u0;
        *(ushort4*)(xb + i + 4) = u1;
        return;
    }
    const float* W;
    unsigned short* O;
    int K, N, n0, k0;
    if (id < 2048) {                       // 512x512 transposes
        const int rid = id - 1024;
        const int mat = rid >> 8, rem = rid & 255;
        W = (mat == 0) ? kw1 : (mat == 1) ? qw1 : (mat == 2) ? vw : ow;
        O = (mat == 0) ? kw1t : (mat == 1) ? qw1t : (mat == 2) ? vwt : owt;
        K = DD; N = DD;
        n0 = (rem & 15) * 32; k0 = (rem >> 4) * 32;
    } else {                               // 512x64 transposes
        const int rid = id - 2048;
        const int mat = rid >> 5, rem = rid & 31;
        W = mat ? qw2 : kw2;
        O = mat ? qw2t : kw2t;
        K = DD; N = TPP;
        n0 = (rem & 1) * 32; k0 = (rem >> 1) * 32;
    }
    const int tx = tid & 31, ty = tid >> 5;  // 32x8
#pragma unroll
    for (int i = 0; i < 4; ++i)
        t[ty + 8 * i][tx] = W[(size_t)(k0 + ty + 8 * i) * N + n0 + tx];
    __syncthreads();
#pragma unroll
    for (int i = 0; i < 4; ++i)
        O[(size_t)(n0 + ty + 8 * i) * K + k0 + tx] = f2bf(t[tx][ty + 8 * i]);
}

// ---------------- fused x-GEMMs: z=0 -> gelu->hkb, z=1 -> gelu->hqb, z=2 -> Vt ----------------
// BM=128, BN=128, BK=64, 256 thr (4 waves, wave tile 64x64). A,Bt k-contiguous bf16.
__global__ __launch_bounds__(256) void mgemm_fused(
    const unsigned short* __restrict__ A,
    const unsigned short* __restrict__ kw1t, const unsigned short* __restrict__ qw1t,
    const unsigned short* __restrict__ vwt,
    const float* __restrict__ kb1, const float* __restrict__ qb1, const float* __restrict__ vb,
    unsigned short* __restrict__ hkb, unsigned short* __restrict__ hqb,
    unsigned short* __restrict__ Vt)
{
    const int z = blockIdx.z;
    const unsigned short* Bt = (z == 0) ? kw1t : (z == 1) ? qw1t : vwt;
    const float* bias = (z == 0) ? kb1 : (z == 1) ? qb1 : vb;
    unsigned short* obf = (z == 0) ? hkb : (z == 1) ? hqb : Vt;
    const int K = DD, N = DD;

    __shared__ unsigned short As[128 * 72];
    __shared__ unsigned short Bs[128 * 72];
    const int tid = threadIdx.x;
    const int w = tid >> 6, lane = tid & 63, grp = lane >> 4, lid = lane & 15;
    const int wr = w >> 1, wc = w & 1;   // wave tile: rows wr*64, cols wc*64
    const int row0 = blockIdx.y * 128, col0 = blockIdx.x * 128;
    f32x4 acc[4][4];
#pragma unroll
    for (int m = 0; m < 4; ++m)
#pragma unroll
        for (int n = 0; n < 4; ++n) acc[m][n] = (f32x4)0.f;

    for (int k0 = 0; k0 < K; k0 += 64) {
        bf16x8 va[4], vbv[4];
#pragma unroll
        for (int i = 0; i < 4; ++i) {
            const int c = tid + i * 256;          // 1024 chunks
            va[i] = *(const bf16x8*)(A + (size_t)(row0 + (c >> 3)) * K + k0 + (c & 7) * 8);
            vbv[i] = *(const bf16x8*)(Bt + (size_t)(col0 + (c >> 3)) * K + k0 + (c & 7) * 8);
        }
        __syncthreads();
#pragma unroll
        for (int i = 0; i < 4; ++i) {
            const int c = tid + i * 256;
            *(bf16x8*)(As + (c >> 3) * 72 + (c & 7) * 8) = va[i];
            *(bf16x8*)(Bs + (c >> 3) * 72 + (c & 7) * 8) = vbv[i];
        }
        __syncthreads();
#pragma unroll
        for (int kk = 0; kk < 2; ++kk) {
            bf16x8 af[4], bfr[4];
#pragma unroll
            for (int m = 0; m < 4; ++m)
                af[m] = *(const bf16x8*)(As + (wr * 64 + m * 16 + lid) * 72 + kk * 32 + grp * 8);
#pragma unroll
            for (int n = 0; n < 4; ++n)
                bfr[n] = *(const bf16x8*)(Bs + (wc * 64 + n * 16 + lid) * 72 + kk * 32 + grp * 8);
#pragma unroll
            for (int m = 0; m < 4; ++m)
#pragma unroll
                for (int n = 0; n < 4; ++n)
                    acc[m][n] = __builtin_amdgcn_mfma_f32_16x16x32_bf16(af[m], bfr[n], acc[m][n], 0, 0, 0);
        }
    }
#pragma unroll
    for (int m = 0; m < 4; ++m) {
#pragma unroll
        for (int n = 0; n < 4; ++n) {
            const int col = col0 + wc * 64 + n * 16 + lid;
            const float bc = bias[col];
            if (z == 2) {
                const int rowb = row0 + wr * 64 + m * 16 + grp * 4;
                const int b = rowb >> 11, l = rowb & (LQ - 1);
                const int c = l >> 6, t0 = l & 63;
                ushort4 u;
                u.x = f2bf(acc[m][n][0] + bc);
                u.y = f2bf(acc[m][n][1] + bc);
                u.z = f2bf(acc[m][n][2] + bc);
                u.w = f2bf(acc[m][n][3] + bc);
                *(ushort4*)(Vt + ((size_t)((b * NC + c) * DD) + col) * TC + t0) = u;
            } else {
#pragma unroll
                for (int r = 0; r < 4; ++r) {
                    const int row = row0 + wr * 64 + m * 16 + grp * 4 + r;
                    float v = acc[m][n][r] + bc;
                    v = 0.5f * v * (1.0f + erff(v * 0.70710678118654752f));
                    obf[(size_t)row * N + col] = f2bf(v);
                }
            }
        }
    }
}

// ---------------- fused phase GEMM: y=0 -> K features, y=1 -> Q features ----------------
// BM=64, N=64, K=512. 4 waves, wave tile 16 rows x 64 cols.
__global__ __launch_bounds__(256) void phase_fused(
    const unsigned short* __restrict__ hkb, const unsigned short* __restrict__ hqb,
    const unsigned short* __restrict__ kw2t, const unsigned short* __restrict__ qw2t,
    const float* __restrict__ kb2, const float* __restrict__ qb2,
    const float* __restrict__ sw,
    unsigned short* __restrict__ CKb, unsigned short* __restrict__ CQb,
    unsigned short* __restrict__ CKt)
{
    const int isq = blockIdx.y;
    const unsigned short* A = isq ? hqb : hkb;
    const unsigned short* Bt = isq ? qw2t : kw2t;
    const float* b2 = isq ? qb2 : kb2;
    unsigned short* FROW = isq ? CQb : CKb;
    const int K = DD;

    __shared__ unsigned short As[64 * 72];
    __shared__ unsigned short Bs[64 * 72];
    const int tid = threadIdx.x;
    const int w = tid >> 6, lane = tid & 63, grp = lane >> 4, lid = lane & 15;
    const int row0 = blockIdx.x * 64;
    f32x4 acc[4];
#pragma unroll
    for (int n = 0; n < 4; ++n) acc[n] = (f32x4)0.f;

    for (int k0 = 0; k0 < K; k0 += 64) {
        bf16x8 va[2], vbv[2];
#pragma unroll
        for (int i = 0; i < 2; ++i) {
            const int c = tid + i * 256;
            va[i] = *(const bf16x8*)(A + (size_t)(row0 + (c >> 3)) * K + k0 + (c & 7) * 8);
            vbv[i] = *(const bf16x8*)(Bt + (size_t)(c >> 3) * K + k0 + (c & 7) * 8);
        }
        __syncthreads();
#pragma unroll
        for (int i = 0; i < 2; ++i) {
            const int c = tid + i * 256;
            *(bf16x8*)(As + (c >> 3) * 72 + (c & 7) * 8) = va[i];
            *(bf16x8*)(Bs + (c >> 3) * 72 + (c & 7) * 8) = vbv[i];
        }
        __syncthreads();
#pragma unroll
        for (int kk = 0; kk < 2; ++kk) {
            bf16x8 af, bfr[4];
            af = *(const bf16x8*)(As + (w * 16 + lid) * 72 + kk * 32 + grp * 8);
#pragma unroll
            for (int n = 0; n < 4; ++n)
                bfr[n] = *(const bf16x8*)(Bs + (n * 16 + lid) * 72 + kk * 32 + grp * 8);
#pragma unroll
            for (int n = 0; n < 4; ++n)
                acc[n] = __builtin_amdgcn_mfma_f32_16x16x32_bf16(af, bfr[n], acc[n], 0, 0, 0);
        }
    }
    float wsm[4] = {1.f, 1.f, 1.f, 1.f};
    if (isq) {
        float s0 = sw[0], s1 = sw[1], s2 = sw[2], s3 = sw[3];
        float mx = fmaxf(fmaxf(s0, s1), fmaxf(s2, s3));
        float e0 = __expf(s0 - mx), e1 = __expf(s1 - mx), e2 = __expf(s2 - mx), e3 = __expf(s3 - mx);
        float inv = 1.0f / (e0 + e1 + e2 + e3);
        wsm[0] = e0 * inv; wsm[1] = e1 * inv; wsm[2] = e2 * inv; wsm[3] = e3 * inv;
    }
#pragma unroll
    for (int n = 0; n < 4; ++n) {
        const int p = n * 16 + lid;
        const float bc = b2[p];
        const float wg = isq ? wsm[p >> 4] : 1.0f;
#pragma unroll
        for (int r = 0; r < 4; ++r) {
            const int row = row0 + w * 16 + grp * 4 + r;
            float u = acc[n][r] + bc;
            float th = 1.0f - 2.0f / (__expf(2.0f * u) + 1.0f);   // tanh(u)
            float ph = th * PI_F;
            float sp, cp;
            __sincosf(ph, &sp, &cp);
            const unsigned short cb = f2bf(cp * wg), sb = f2bf(sp * wg);
            FROW[(size_t)row * FF + 2 * p + 0] = cb;
            FROW[(size_t)row * FF + 2 * p + 1] = sb;
            if (!isq) {
                const int b = row >> 11, l = row & (LQ - 1);
                const int c = l >> 6, t = l & 63;
                const size_t base = ((size_t)(b * NC + c) * FF) * TC;
                CKt[base + (size_t)(2 * p + 0) * TC + t] = cb;
                CKt[base + (size_t)(2 * p + 1) * TC + t] = sb;
            }
        }
    }
}

// ---------------- pass A: per-chunk state (bf16) Stp[b][c][d][f] = sum_t Vt[d][t]*CKt[f][t] ----------------
__global__ __launch_bounds__(256) void passA_mfma(
    const unsigned short* __restrict__ Vt, const unsigned short* __restrict__ CKt,
    unsigned short* __restrict__ Stp)
{
    const int tid = threadIdx.x;
    const int w = tid >> 6, lane = tid & 63, grp = lane >> 4, lid = lane & 15;
    const int dq = blockIdx.x, c = blockIdx.y, b = blockIdx.z;
    const int d0 = dq * 128 + w * 32;
    const size_t cb = (size_t)(b * NC + c);
    f32x4 acc[2][8];
#pragma unroll
    for (int md = 0; md < 2; ++md)
#pragma unroll
        for (int nf = 0; nf < 8; ++nf) acc[md][nf] = (f32x4)0.f;
#pragma unroll
    for (int kt = 0; kt < 2; ++kt) {
        bf16x8 av[2], bk[8];
#pragma unroll
        for (int md = 0; md < 2; ++md)
            av[md] = *(const bf16x8*)(Vt + (cb * DD + d0 + md * 16 + lid) * TC + kt * 32 + grp * 8);
#pragma unroll
        for (int nf = 0; nf < 8; ++nf)
            bk[nf] = *(const bf16x8*)(CKt + (cb * FF + nf * 16 + lid) * TC + kt * 32 + grp * 8);
#pragma unroll
        for (int md = 0; md < 2; ++md)
#pragma unroll
            for (int nf = 0; nf < 8; ++nf)
                acc[md][nf] = __builtin_amdgcn_mfma_f32_16x16x32_bf16(av[md], bk[nf], acc[md][nf], 0, 0, 0);
    }
#pragma unroll
    for (int md = 0; md < 2; ++md)
#pragma unroll
        for (int nf = 0; nf < 8; ++nf)
#pragma unroll
            for (int r = 0; r < 4; ++r) {
                const int d = d0 + md * 16 + grp * 4 + r;
                const int f = nf * 16 + lid;
                Stp[(cb * DD + d) * FF + f] = f2bf(acc[md][nf][r]);
            }
}

// ---------------- pass B: exclusive prefix over chunks (bf16 in, f32 run, bf16 out) ----------------
__global__ __launch_bounds__(256) void prefix_mfma(
    const unsigned short* __restrict__ Stp, unsigned short* __restrict__ Stb)
{
    const int gid = blockIdx.x * 256 + threadIdx.x;  // b*(DD*FF) + d*FF + f
    const int b = gid >> 16;                          // DD*FF = 65536
    const int df = gid & 65535;
    float run = 0.f;
#pragma unroll
    for (int c = 0; c < NC; ++c) {
        const size_t idx = ((size_t)(b * NC + c) << 16) + df;
        Stb[idx] = f2bf(run);
        run += bf2f(Stp[idx]);
    }
}

// ---------------- pass C: r = tril(CQ CK^T) V + CQ S_prefix ----------------
__global__ __launch_bounds__(128) void passC_mfma(
    const unsigned short* __restrict__ CQb, const unsigned short* __restrict__ CKb,
    const unsigned short* __restrict__ Vt, const unsigned short* __restrict__ Stb,
    float* __restrict__ R)
{
    __shared__ unsigned short P[64][72];
    const int tid = threadIdx.x;
    const int w = tid >> 6, lane = tid & 63, grp = lane >> 4, lid = lane & 15;
    const int dh = blockIdx.x, c = blockIdx.y, b = blockIdx.z;
    const size_t rowbase = (size_t)b * LQ + c * 64;
    const size_t cb = (size_t)(b * NC + c);
    f32x4 qk[2][4];
#pragma unroll
    for (int mi = 0; mi < 2; ++mi)
#pragma unroll
        for (int nt = 0; nt < 4; ++nt) qk[mi][nt] = (f32x4)0.f;
#pragma unroll
    for (int kf = 0; kf < 4; ++kf) {
        bf16x8 aq[2], bk[4];
#pragma unroll
        for (int mi = 0; mi < 2; ++mi)
            aq[mi] = *(const bf16x8*)(CQb + (rowbase + (2 * w + mi) * 16 + lid) * FF + kf * 32 + grp * 8);
#pragma unroll
        for (int nt = 0; nt < 4; ++nt)
            bk[nt] = *(const bf16x8*)(CKb + (rowbase + nt * 16 + lid) * FF + kf * 32 + grp * 8);
#pragma unroll
        for (int mi = 0; mi < 2; ++mi)
#pragma unroll
            for (int nt = 0; nt < 4; ++nt)
                qk[mi][nt] = __builtin_amdgcn_mfma_f32_16x16x32_bf16(aq[mi], bk[nt], qk[mi][nt], 0, 0, 0);
    }
#pragma unroll
    for (int mi = 0; mi < 2; ++mi)
#pragma unroll
        for (int nt = 0; nt < 4; ++nt)
#pragma unroll
            for (int r = 0; r < 4; ++r) {
                const int row = (2 * w + mi) * 16 + grp * 4 + r;
                const int col = nt * 16 + lid;
                P[row][col] = f2bf(col <= row ? qk[mi][nt][r] : 0.f);
            }
    __syncthreads();
    const int d0 = dh * 128 + w * 64;
    f32x4 racc[4][4];
#pragma unroll
    for (int ml = 0; ml < 4; ++ml)
#pragma unroll
        for (int nd = 0; nd < 4; ++nd) racc[ml][nd] = (f32x4)0.f;
#pragma unroll
    for (int kt = 0; kt < 2; ++kt) {
        bf16x8 ap[4], bv[4];
#pragma unroll
        for (int ml = 0; ml < 4; ++ml)
            ap[ml] = *(const bf16x8*)&P[ml * 16 + lid][kt * 32 + grp * 8];
#pragma unroll
        for (int nd = 0; nd < 4; ++nd)
            bv[nd] = *(const bf16x8*)(Vt + (cb * DD + d0 + nd * 16 + lid) * TC + kt * 32 + grp * 8);
#pragma unroll
        for (int ml = 0; ml < 4; ++ml)
#pragma unroll
            for (int nd = 0; nd < 4; ++nd)
                racc[ml][nd] = __builtin_amdgcn_mfma_f32_16x16x32_bf16(ap[ml], bv[nd], racc[ml][nd], 0, 0, 0);
    }
#pragma unroll
    for (int kf = 0; kf < 4; ++kf) {
        bf16x8 aq[4], bs[4];
#pragma unroll
        for (int ml = 0; ml < 4; ++ml)
            aq[ml] = *(const bf16x8*)(CQb + (rowbase + ml * 16 + lid) * FF + kf * 32 + grp * 8);
#pragma unroll
        for (int nd = 0; nd < 4; ++nd)
            bs[nd] = *(const bf16x8*)(Stb + (cb * DD + d0 + nd * 16 + lid) * FF + kf * 32 + grp * 8);
#pragma unroll
        for (int ml = 0; ml < 4; ++ml)
#pragma unroll
            for (int nd = 0; nd < 4; ++nd)
                racc[ml][nd] = __builtin_amdgcn_mfma_f32_16x16x32_bf16(aq[ml], bs[nd], racc[ml][nd], 0, 0, 0);
    }
#pragma unroll
    for (int ml = 0; ml < 4; ++ml)
#pragma unroll
        for (int nd = 0; nd < 4; ++nd)
#pragma unroll
            for (int r = 0; r < 4; ++r) {
                const int l = ml * 16 + grp * 4 + r;
                const int d = d0 + nd * 16 + lid;
                R[(rowbase + l) * DD + d] = racc[ml][nd][r];
            }
}

// ---------------- position norm + LayerNorm (bf16 out) ----------------
__global__ __launch_bounds__(256) void ln_kernel(
    const float* __restrict__ R, const float* __restrict__ g,
    const float* __restrict__ be, unsigned short* __restrict__ YN)
{
    const int row = blockIdx.x;
    const int l = row & (LQ - 1);
    const int tid = threadIdx.x;
    const float pscale = rsqrtf((float)((l + 1) * PPL));
    float y0 = R[(size_t)row * DD + tid] * pscale;
    float y1 = R[(size_t)row * DD + 256 + tid] * pscale;
    float s = y0 + y1;
    float q = y0 * y0 + y1 * y1;
#pragma unroll
    for (int off = 32; off >= 1; off >>= 1) {
        s += __shfl_xor(s, off, 64);
        q += __shfl_xor(q, off, 64);
    }
    __shared__ float rs[4], rq[4];
    const int wid = tid >> 6, lane = tid & 63;
    if (lane == 0) { rs[wid] = s; rq[wid] = q; }
    __syncthreads();
    const float ts = rs[0] + rs[1] + rs[2] + rs[3];
    const float tq = rq[0] + rq[1] + rq[2] + rq[3];
    const float mu = ts * (1.0f / DD);
    float var = tq * (1.0f / DD) - mu * mu;
    const float rstd = rsqrtf(var + 1e-5f);
    YN[(size_t)row * DD + tid] = f2bf((y0 - mu) * rstd * g[tid] + be[tid]);
    YN[(size_t)row * DD + 256 + tid] = f2bf((y1 - mu) * rstd * g[tid + 256] + be[tid + 256]);
}

// ---------------- output GEMM: BM=128, BN=64, out = acc + bias + resid ----------------
__global__ __launch_bounds__(256) void mgemm_out(
    const unsigned short* __restrict__ A, const unsigned short* __restrict__ Bt,
    const float* __restrict__ bias, const float* __restrict__ resid,
    float* __restrict__ out)
{
    const int K = DD, N = DD;
    __shared__ unsigned short As[128 * 72];
    __shared__ unsigned short Bs[64 * 72];
    const int tid = threadIdx.x;
    const int w = tid >> 6, lane = tid & 63, grp = lane >> 4, lid = lane & 15;
    const int wr = w >> 1, wc = w & 1;   // wave tile: rows wr*64, cols wc*32
    const int row0 = blockIdx.y * 128, col0 = blockIdx.x * 64;
    f32x4 acc[4][2];
#pragma unroll
    for (int m = 0; m < 4; ++m)
#pragma unroll
        for (int n = 0; n < 2; ++n) acc[m][n] = (f32x4)0.f;

    for (int k0 = 0; k0 < K; k0 += 64) {
        bf16x8 va[4], vbv[2];
#pragma unroll
        for (int i = 0; i < 4; ++i) {
            const int c = tid + i * 256;
            va[i] = *(const bf16x8*)(A + (size_t)(row0 + (c >> 3)) * K + k0 + (c & 7) * 8);
        }
#pragma unroll
        for (int i = 0; i < 2; ++i) {
            const int c = tid + i * 256;
            vbv[i] = *(const bf16x8*)(Bt + (size_t)(col0 + (c >> 3)) * K + k0 + (c & 7) * 8);
        }
        __syncthreads();
#pragma unroll
        for (int i = 0; i < 4; ++i) {
            const int c = tid + i * 256;
            *(bf16x8*)(As + (c >> 3) * 72 + (c & 7) * 8) = va[i];
        }
#pragma unroll
        for (int i = 0; i < 2; ++i) {
            const int c = tid + i * 256;
            *(bf16x8*)(Bs + (c >> 3) * 72 + (c & 7) * 8) = vbv[i];
        }
        __syncthreads();
#pragma unroll
        for (int kk = 0; kk < 2; ++kk) {
            bf16x8 af[4], bfr[2];
#pragma unroll
            for (int m = 0; m < 4; ++m)
                af[m] = *(const bf16x8*)(As + (wr * 64 + m * 16 + lid) * 72 + kk * 32 + grp * 8);
#pragma unroll
            for (int n = 0; n < 2; ++n)
                bfr[n] = *(const bf16x8*)(Bs + (wc * 32 + n * 16 + lid) * 72 + kk * 32 + grp * 8);
#pragma unroll
            for (int m = 0; m < 4; ++m)
#pragma unroll
                for (int n = 0; n < 2; ++n)
                    acc[m][n] = __builtin_amdgcn_mfma_f32_16x16x32_bf16(af[m], bfr[n], acc[m][n], 0, 0, 0);
        }
    }
#pragma unroll
    for (int m = 0; m < 4; ++m) {
#pragma unroll
        for (int n = 0; n < 2; ++n) {
            const int col = col0 + wc * 32 + n * 16 + lid;
            const float bc = bias[col];
#pragma unroll
            for (int r = 0; r < 4; ++r) {
                const int row = row0 + wr * 64 + m * 16 + grp * 4 + r;
                out[(size_t)row * N + col] = acc[m][n][r] + bc + resid[(size_t)row * N + col];
            }
        }
    }
}

extern "C" void kernel_launch(void* const* d_in, const int* in_sizes, int n_in,
                              void* d_out, int out_size, void* d_ws, size_t ws_size,
                              hipStream_t stream)
{
    const float* x   = (const float*)d_in[0];
    const float* sw  = (const float*)d_in[1];
    const float* kw1 = (const float*)d_in[2];
    const float* kb1 = (const float*)d_in[3];
    const float* kw2 = (const float*)d_in[4];
    const float* kb2 = (const float*)d_in[5];
    const float* qw1 = (const float*)d_in[6];
    const float* qb1 = (const float*)d_in[7];
    const float* qw2 = (const float*)d_in[8];
    const float* qb2 = (const float*)d_in[9];
    const float* vw  = (const float*)d_in[10];
    const float* vb  = (const float*)d_in[11];
    const float* lng = (const float*)d_in[12];
    const float* lnb = (const float*)d_in[13];
    const float* ow  = (const float*)d_in[14];
    const float* ob  = (const float*)d_in[15];
    float* out = (float*)d_out;

    const size_t MR = (size_t)NB * LQ;  // 4096 rows
    float* ws = (float*)d_ws;
    float* Rb = ws;                                   // 2M f32
    unsigned short* xb   = (unsigned short*)(Rb + MR * DD);
    unsigned short* hkb  = xb + MR * DD;
    unsigned short* hqb  = hkb + MR * DD;
    unsigned short* YNb  = hqb + MR * DD;
    unsigned short* Vt   = YNb + MR * DD;
    unsigned short* CQb  = Vt + MR * DD;
    unsigned short* CKb  = CQb + MR * FF;
    unsigned short* CKt  = CKb + MR * FF;
    unsigned short* Stp  = CKt + MR * FF;             // 4M shorts
    unsigned short* Stb  = Stp + (size_t)NB * NC * DD * FF;  // 4M shorts
    unsigned short* kw1t = Stb + (size_t)NB * NC * DD * FF;
    unsigned short* qw1t = kw1t + (size_t)DD * DD;
    unsigned short* vwt  = qw1t + (size_t)DD * DD;
    unsigned short* owt  = vwt + (size_t)DD * DD;
    unsigned short* kw2t = owt + (size_t)DD * DD;
    unsigned short* qw2t = kw2t + (size_t)TPP * DD;

    const dim3 blk(256);
    hipLaunchKernelGGL(prep_kernel, dim3(2112), blk, 0, stream,
                       x, kw1, qw1, vw, ow, kw2, qw2,
                       xb, kw1t, qw1t, vwt, owt, kw2t, qw2t);
    hipLaunchKernelGGL(mgemm_fused, dim3(DD / 128, MR / 128, 3), blk, 0, stream,
                       xb, kw1t, qw1t, vwt, kb1, qb1, vb, hkb, hqb, Vt);
    hipLaunchKernelGGL(phase_fused, dim3(MR / 64, 2), blk, 0, stream,
                       hkb, hqb, kw2t, qw2t, kb2, qb2, sw, CKb, CQb, CKt);
    hipLaunchKernelGGL(passA_mfma, dim3(4, NC, NB), blk, 0, stream, Vt, CKt, Stp);
    hipLaunchKernelGGL(prefix_mfma, dim3((NB * DD * FF) / 256), blk, 0, stream, Stp, Stb);
    hipLaunchKernelGGL(passC_mfma, dim3(4, NC, NB), dim3(128), 0, stream, CQb, CKb, Vt, Stb, Rb);
    hipLaunchKernelGGL(ln_kernel, dim3((unsigned)MR), blk, 0, stream, Rb, lng, lnb, YNb);
    hipLaunchKernelGGL(mgemm_out, dim3(DD / 64, MR / 128), blk, 0, stream, YNb, owt, ob, x, out);
}